// Round 10
// baseline (172.295 us; speedup 1.0000x reference)
//
#include <hip/hip_runtime.h>

// 9x9 box filter (r=4), reflect padding, 24 planes of 2048x2048 f32.
// R10 = R9 (3-deep software-pipelined loads, 4 cols/thread, folded
// race-free edge blocks) with RH 32->64: vertical halo 1.25x -> 1.125x
// (-48 MB reads), and 72 steps = 8 groups of 9 -> ZERO tail; phase (s%9)
// and slot (s%3) both stay compile-time through uniform groups of 9.
// Grid: 1536 main + 192 edge blocks, single dispatch, disjoint writes.
// SROA rules: float4 temps only, all array indices compile-time.

constexpr int H   = 2048;
constexpr int W   = 2048;
constexpr int R   = 4;              // radius (reference uses r=4)
constexpr int RH  = 64;             // output rows per block (72 input rows)
constexpr int TPB = 256;
constexpr int CPT = 4;              // cols per thread
constexpr int BCOLS = TPB * CPT;    // 1024 cols per block (2 halves per row)
constexpr int STEPS = RH + 2 * R;   // 72 input-row steps = 8 * 9

typedef float f32x4 __attribute__((ext_vector_type(4)));

struct Slot { float4 A, B, C; };    // 12 floats: rowp[off .. off+11]

__device__ __forceinline__ int reflect_row(int r) {
  r = (r < 0) ? -r : r;
  return (r >= H) ? (2 * H - 2 - r) : r;
}

template <int K>
__device__ __forceinline__ void issue_load(int s, int r0, int off,
                                           const float* __restrict__ px,
                                           Slot (&sl)[3]) {
  const int lr = reflect_row(r0 - R + s);
  const float* __restrict__ rowp = px + (size_t)lr * W + off;
  sl[K].A = *(const float4*)(rowp);
  sl[K].B = *(const float4*)(rowp + 4);
  sl[K].C = *(const float4*)(rowp + 8);
}

// P = ring phase (s%9), K = pipeline slot (s%3) -- both compile-time.
// PF: issue this slot's load for step s+3 (skipped on the last 3 steps).
template <int P, int K, bool STORE, bool PF>
__device__ __forceinline__ void bf_step(
    int s, int r0, int off, int c0, bool doStore,
    const float* __restrict__ px, float* __restrict__ po,
    Slot (&sl)[3], float (&hbuf)[9][CPT], float (&vsum)[CPT]) {
  const float4 A = sl[K].A;
  const float4 B = sl[K].B;
  const float4 C = sl[K].C;

  if (PF) issue_load<K>(s + 3, r0, off, px, sl);   // prefetch 3 steps ahead

  float h0 = ((A.x + A.y) + (A.z + A.w)) +
             ((B.x + B.y) + (B.z + B.w)) + C.x;
  float h1 = h0 + C.y - A.x;
  float h2 = h1 + C.z - A.y;
  float h3 = h2 + C.w - A.z;

  vsum[0] += h0 - hbuf[P][0]; hbuf[P][0] = h0;
  vsum[1] += h1 - hbuf[P][1]; hbuf[P][1] = h1;
  vsum[2] += h2 - hbuf[P][2]; hbuf[P][2] = h2;
  vsum[3] += h3 - hbuf[P][3]; hbuf[P][3] = h3;

  if (STORE) {
    if (doStore) {
      const float inv81 = 1.0f / 81.0f;
      float* o = po + (size_t)(r0 + s - 2 * R) * W + c0;
      f32x4 ov = {vsum[0] * inv81, vsum[1] * inv81,
                  vsum[2] * inv81, vsum[3] * inv81};
      __builtin_nontemporal_store(ov, (f32x4*)o);
    }
  }
}

__global__ __launch_bounds__(TPB, 4) void BoxFilter_kernel(
    const float* __restrict__ x, float* __restrict__ out, int nMain) {
  const int t   = threadIdx.x;
  const int bid = blockIdx.x;

  if (bid >= nMain) {
    // ---- edge path: exact recompute of cols 0..3 and W-4..W-1 per row ----
    const int idx   = (bid - nMain) * TPB + t;   // 0 .. planes*H-1
    const int plane = idx >> 11;
    const int r     = idx & (H - 1);
    const float* __restrict__ px = x   + (size_t)plane * H * W;
    float*       __restrict__ po = out + (size_t)plane * H * W;

    float accL[4] = {0.f, 0.f, 0.f, 0.f};
    float accR[4] = {0.f, 0.f, 0.f, 0.f};
#pragma unroll
    for (int dr = -R; dr <= R; ++dr) {
      const int rr = reflect_row(r + dr);
      const float* __restrict__ rowp = px + (size_t)rr * W;
      float l[9], m[9];
#pragma unroll
      for (int i = 0; i < 9; ++i) l[i] = rowp[i];          // cols 0..8
#pragma unroll
      for (int i = 0; i < 9; ++i) m[i] = rowp[W - 9 + i];  // cols W-9..W-1
#pragma unroll
      for (int c = 0; c < 4; ++c) {
#pragma unroll
        for (int k = -R; k <= R; ++k) {
          int j = c + k; j = (j < 0) ? -j : j;             // left col reflect
          accL[c] += l[j];
          int rc = (W - 4 + c) + k;
          rc = (rc >= W) ? (2 * W - 2 - rc) : rc;          // right col reflect
          accR[c] += m[rc - (W - 9)];
        }
      }
    }
    const float inv81 = 1.0f / 81.0f;
    float* oL = po + (size_t)r * W;
    float* oR = po + (size_t)r * W + (W - 4);
    f32x4 vL = {accL[0] * inv81, accL[1] * inv81,
                accL[2] * inv81, accL[3] * inv81};
    f32x4 vR = {accR[0] * inv81, accR[1] * inv81,
                accR[2] * inv81, accR[3] * inv81};
    *(f32x4*)oL = vL;
    *(f32x4*)oR = vR;
    return;
  }

  // ---- main path (natural block order) ----
  const int plane = bid >> 6;          // 32 chunks * 2 halves per plane
  const int rem   = bid & 63;
  const int chunk = rem >> 1;
  const int half  = rem & 1;
  const int r0    = chunk * RH;
  const int cb    = half * BCOLS;
  const float* __restrict__ px = x   + (size_t)plane * H * W;
  float*       __restrict__ po = out + (size_t)plane * H * W;

  const int c0 = cb + t * CPT;         // first output col (16B aligned)
  int off = c0 - R;                    // clamped load base (16B aligned)
  off = off < 0 ? 0 : off;
  off = off > W - 12 ? W - 12 : off;   // 2036, still 16B aligned
  const bool doStore = (c0 != 0) && (c0 != W - CPT);  // edge blocks own those

  float hbuf[9][CPT];
  float vsum[CPT];
#pragma unroll
  for (int j = 0; j < CPT; ++j) vsum[j] = 0.0f;
#pragma unroll
  for (int p = 0; p < 9; ++p)
#pragma unroll
    for (int j = 0; j < CPT; ++j) hbuf[p][j] = 0.0f;

  Slot sl[3];
  issue_load<0>(0, r0, off, px, sl);
  issue_load<1>(1, r0, off, px, sl);
  issue_load<2>(2, r0, off, px, sl);

  // warmup group: s = 0..8 (phases 0..8, slots s%3); store only at s=8
  bf_step<0, 0, false, true>(0, r0, off, c0, doStore, px, po, sl, hbuf, vsum);
  bf_step<1, 1, false, true>(1, r0, off, c0, doStore, px, po, sl, hbuf, vsum);
  bf_step<2, 2, false, true>(2, r0, off, c0, doStore, px, po, sl, hbuf, vsum);
  bf_step<3, 0, false, true>(3, r0, off, c0, doStore, px, po, sl, hbuf, vsum);
  bf_step<4, 1, false, true>(4, r0, off, c0, doStore, px, po, sl, hbuf, vsum);
  bf_step<5, 2, false, true>(5, r0, off, c0, doStore, px, po, sl, hbuf, vsum);
  bf_step<6, 0, false, true>(6, r0, off, c0, doStore, px, po, sl, hbuf, vsum);
  bf_step<7, 1, false, true>(7, r0, off, c0, doStore, px, po, sl, hbuf, vsum);
  bf_step<8, 2, true,  true>(8, r0, off, c0, doStore, px, po, sl, hbuf, vsum);

  // steady: s = 9..62, six full groups of 9 (s0 % 9 == 0 and % 3 == 0)
#pragma unroll 1
  for (int s0 = 9; s0 <= 54; s0 += 9) {
    bf_step<0, 0, true, true>(s0 + 0, r0, off, c0, doStore, px, po, sl, hbuf, vsum);
    bf_step<1, 1, true, true>(s0 + 1, r0, off, c0, doStore, px, po, sl, hbuf, vsum);
    bf_step<2, 2, true, true>(s0 + 2, r0, off, c0, doStore, px, po, sl, hbuf, vsum);
    bf_step<3, 0, true, true>(s0 + 3, r0, off, c0, doStore, px, po, sl, hbuf, vsum);
    bf_step<4, 1, true, true>(s0 + 4, r0, off, c0, doStore, px, po, sl, hbuf, vsum);
    bf_step<5, 2, true, true>(s0 + 5, r0, off, c0, doStore, px, po, sl, hbuf, vsum);
    bf_step<6, 0, true, true>(s0 + 6, r0, off, c0, doStore, px, po, sl, hbuf, vsum);
    bf_step<7, 1, true, true>(s0 + 7, r0, off, c0, doStore, px, po, sl, hbuf, vsum);
    bf_step<8, 2, true, true>(s0 + 8, r0, off, c0, doStore, px, po, sl, hbuf, vsum);
  }
  // last group: s = 63..71; final 3 steps skip prefetch
  bf_step<0, 0, true, true >(63, r0, off, c0, doStore, px, po, sl, hbuf, vsum);
  bf_step<1, 1, true, true >(64, r0, off, c0, doStore, px, po, sl, hbuf, vsum);
  bf_step<2, 2, true, true >(65, r0, off, c0, doStore, px, po, sl, hbuf, vsum);
  bf_step<3, 0, true, true >(66, r0, off, c0, doStore, px, po, sl, hbuf, vsum);
  bf_step<4, 1, true, true >(67, r0, off, c0, doStore, px, po, sl, hbuf, vsum);
  bf_step<5, 2, true, true >(68, r0, off, c0, doStore, px, po, sl, hbuf, vsum);
  bf_step<6, 0, true, false>(69, r0, off, c0, doStore, px, po, sl, hbuf, vsum);
  bf_step<7, 1, true, false>(70, r0, off, c0, doStore, px, po, sl, hbuf, vsum);
  bf_step<8, 2, true, false>(71, r0, off, c0, doStore, px, po, sl, hbuf, vsum);
}

extern "C" void kernel_launch(void* const* d_in, const int* in_sizes, int n_in,
                              void* d_out, int out_size, void* d_ws, size_t ws_size,
                              hipStream_t stream) {
  const float* x   = (const float*)d_in[0];
  float*       out = (float*)d_out;
  const int planes = out_size / (H * W);              // 8*3 = 24
  const int nMain  = planes * (H / RH) * 2;           // 24*32*2 = 1536
  const int nEdge  = planes * H / TPB;                // 192
  dim3 grid(nMain + nEdge);
  dim3 block(TPB);
  hipLaunchKernelGGL(BoxFilter_kernel, grid, block, 0, stream, x, out, nMain);
}

// Round 11
// 151.620 us; speedup vs baseline: 1.1364x; 1.1364x over previous
//
#include <hip/hip_runtime.h>

// 9x9 box filter (r=4), reflect padding, 24 planes of 2048x2048 f32.
// R11 = R10 main path (3-deep pipelined loads, 4 cols/thread, RH=64,
// race-free column ownership) + rewritten edge path:
//  - edge blocks FIRST in the grid (overlap main, not a latency tail),
//  - separable: phase 1 computes per-row horizontal edge sums h once per
//    row (4 aligned float4 loads/thread) into LDS [8][264] (column-major
//    slots -> conflict-free banked reads); phase 2 does the vertical 9-sum
//    from LDS. 162 scalar scattered loads/thread -> ~5 vectorized ones.
// Ownership unchanged: edge owns cols {0..3, W-4..W-1}; main lanes skip.
// SROA rules: float4 temps only, all array indices compile-time.

constexpr int H   = 2048;
constexpr int W   = 2048;
constexpr int R   = 4;              // radius (reference uses r=4)
constexpr int RH  = 64;             // output rows per block (72 input rows)
constexpr int TPB = 256;
constexpr int CPT = 4;              // cols per thread
constexpr int BCOLS = TPB * CPT;    // 1024 cols per block (2 halves per row)

typedef float f32x4 __attribute__((ext_vector_type(4)));

struct Slot { float4 A, B, C; };    // 12 floats: rowp[off .. off+11]

__device__ __forceinline__ int reflect_row(int r) {
  r = (r < 0) ? -r : r;
  return (r >= H) ? (2 * H - 2 - r) : r;
}

template <int K>
__device__ __forceinline__ void issue_load(int s, int r0, int off,
                                           const float* __restrict__ px,
                                           Slot (&sl)[3]) {
  const int lr = reflect_row(r0 - R + s);
  const float* __restrict__ rowp = px + (size_t)lr * W + off;
  sl[K].A = *(const float4*)(rowp);
  sl[K].B = *(const float4*)(rowp + 4);
  sl[K].C = *(const float4*)(rowp + 8);
}

// P = ring phase (s%9), K = pipeline slot (s%3) -- both compile-time.
// PF: issue this slot's load for step s+3 (skipped on the last 3 steps).
template <int P, int K, bool STORE, bool PF>
__device__ __forceinline__ void bf_step(
    int s, int r0, int off, int c0, bool doStore,
    const float* __restrict__ px, float* __restrict__ po,
    Slot (&sl)[3], float (&hbuf)[9][CPT], float (&vsum)[CPT]) {
  const float4 A = sl[K].A;
  const float4 B = sl[K].B;
  const float4 C = sl[K].C;

  if (PF) issue_load<K>(s + 3, r0, off, px, sl);   // prefetch 3 steps ahead

  float h0 = ((A.x + A.y) + (A.z + A.w)) +
             ((B.x + B.y) + (B.z + B.w)) + C.x;
  float h1 = h0 + C.y - A.x;
  float h2 = h1 + C.z - A.y;
  float h3 = h2 + C.w - A.z;

  vsum[0] += h0 - hbuf[P][0]; hbuf[P][0] = h0;
  vsum[1] += h1 - hbuf[P][1]; hbuf[P][1] = h1;
  vsum[2] += h2 - hbuf[P][2]; hbuf[P][2] = h2;
  vsum[3] += h3 - hbuf[P][3]; hbuf[P][3] = h3;

  if (STORE) {
    if (doStore) {
      const float inv81 = 1.0f / 81.0f;
      float* o = po + (size_t)(r0 + s - 2 * R) * W + c0;
      f32x4 ov = {vsum[0] * inv81, vsum[1] * inv81,
                  vsum[2] * inv81, vsum[3] * inv81};
      __builtin_nontemporal_store(ov, (f32x4*)o);
    }
  }
}

__global__ __launch_bounds__(TPB, 4) void BoxFilter_kernel(
    const float* __restrict__ x, float* __restrict__ out, int nEdge) {
  const int t   = threadIdx.x;
  const int bid = blockIdx.x;

  if (bid < nEdge) {
    // ---- edge path: separable recompute of cols {0..3, W-4..W-1} ----
    // One block = 256 consecutive rows of one plane (8 bands/plane).
    __shared__ float hAll[8][264];      // [c: 0..3 left, 4..7 right][slot]
    const int plane = bid >> 3;
    const int r0e   = (bid & 7) * TPB;  // first output row of this band
    const float* __restrict__ px = x   + (size_t)plane * H * W;
    float*       __restrict__ po = out + (size_t)plane * H * W;

    // phase 1: horizontal 9-sums for rows r0e-4 .. r0e+259 (slot = row - (r0e-4))
    auto compute_h = [&](int slot) {
      const int rr = reflect_row(r0e - 4 + slot);
      const float* __restrict__ rowp = px + (size_t)rr * W;
      const float4 L0 = *(const float4*)(rowp);          // cols 0..3
      const float4 L1 = *(const float4*)(rowp + 4);      // cols 4..7
      const float4 R0 = *(const float4*)(rowp + W - 8);  // cols 2040..2043
      const float4 R1 = *(const float4*)(rowp + W - 4);  // cols 2044..2047
      const float l[8] = {L0.x, L0.y, L0.z, L0.w, L1.x, L1.y, L1.z, L1.w};
      const float m[8] = {R0.x, R0.y, R0.z, R0.w, R1.x, R1.y, R1.z, R1.w};
#pragma unroll
      for (int c = 0; c < 4; ++c) {
        float aL = 0.f, aR = 0.f;
#pragma unroll
        for (int k = -R; k <= R; ++k) {
          int j = c + k; j = (j < 0) ? -j : j;           // 0..7
          aL += l[j];
          int q = (W - 4 + c) + k;
          q = (q >= W) ? (2 * W - 2 - q) : q;            // 2040..2047
          aR += m[q - (W - 8)];
        }
        hAll[c][slot]     = aL;
        hAll[4 + c][slot] = aR;
      }
    };
    compute_h(t + 4);                       // own row
    if (t < 4)        compute_h(t);         // top halo (slots 0..3)
    else if (t >= TPB - 4) compute_h(t + 8);// bottom halo (slots 260..263)
    __syncthreads();

    // phase 2: vertical 9-sum; lane t reads slots t..t+8 (conflict-free)
    float accL[4] = {0.f, 0.f, 0.f, 0.f};
    float accR[4] = {0.f, 0.f, 0.f, 0.f};
#pragma unroll
    for (int d = 0; d < 9; ++d) {
#pragma unroll
      for (int c = 0; c < 4; ++c) {
        accL[c] += hAll[c][t + d];
        accR[c] += hAll[4 + c][t + d];
      }
    }
    const float inv81 = 1.0f / 81.0f;
    const int r = r0e + t;
    f32x4 vL = {accL[0] * inv81, accL[1] * inv81,
                accL[2] * inv81, accL[3] * inv81};
    f32x4 vR = {accR[0] * inv81, accR[1] * inv81,
                accR[2] * inv81, accR[3] * inv81};
    *(f32x4*)(po + (size_t)r * W)           = vL;
    *(f32x4*)(po + (size_t)r * W + (W - 4)) = vR;
    return;
  }

  // ---- main path (identical to R10) ----
  const int mbid  = bid - nEdge;
  const int plane = mbid >> 6;         // 32 chunks * 2 halves per plane
  const int rem   = mbid & 63;
  const int chunk = rem >> 1;
  const int half  = rem & 1;
  const int r0    = chunk * RH;
  const int cb    = half * BCOLS;
  const float* __restrict__ px = x   + (size_t)plane * H * W;
  float*       __restrict__ po = out + (size_t)plane * H * W;

  const int c0 = cb + t * CPT;         // first output col (16B aligned)
  int off = c0 - R;                    // clamped load base (16B aligned)
  off = off < 0 ? 0 : off;
  off = off > W - 12 ? W - 12 : off;   // 2036, still 16B aligned
  const bool doStore = (c0 != 0) && (c0 != W - CPT);  // edge blocks own those

  float hbuf[9][CPT];
  float vsum[CPT];
#pragma unroll
  for (int j = 0; j < CPT; ++j) vsum[j] = 0.0f;
#pragma unroll
  for (int p = 0; p < 9; ++p)
#pragma unroll
    for (int j = 0; j < CPT; ++j) hbuf[p][j] = 0.0f;

  Slot sl[3];
  issue_load<0>(0, r0, off, px, sl);
  issue_load<1>(1, r0, off, px, sl);
  issue_load<2>(2, r0, off, px, sl);

  // warmup group: s = 0..8 (phases 0..8, slots s%3); store only at s=8
  bf_step<0, 0, false, true>(0, r0, off, c0, doStore, px, po, sl, hbuf, vsum);
  bf_step<1, 1, false, true>(1, r0, off, c0, doStore, px, po, sl, hbuf, vsum);
  bf_step<2, 2, false, true>(2, r0, off, c0, doStore, px, po, sl, hbuf, vsum);
  bf_step<3, 0, false, true>(3, r0, off, c0, doStore, px, po, sl, hbuf, vsum);
  bf_step<4, 1, false, true>(4, r0, off, c0, doStore, px, po, sl, hbuf, vsum);
  bf_step<5, 2, false, true>(5, r0, off, c0, doStore, px, po, sl, hbuf, vsum);
  bf_step<6, 0, false, true>(6, r0, off, c0, doStore, px, po, sl, hbuf, vsum);
  bf_step<7, 1, false, true>(7, r0, off, c0, doStore, px, po, sl, hbuf, vsum);
  bf_step<8, 2, true,  true>(8, r0, off, c0, doStore, px, po, sl, hbuf, vsum);

  // steady: s = 9..62, six full groups of 9 (s0 % 9 == 0 and % 3 == 0)
#pragma unroll 1
  for (int s0 = 9; s0 <= 54; s0 += 9) {
    bf_step<0, 0, true, true>(s0 + 0, r0, off, c0, doStore, px, po, sl, hbuf, vsum);
    bf_step<1, 1, true, true>(s0 + 1, r0, off, c0, doStore, px, po, sl, hbuf, vsum);
    bf_step<2, 2, true, true>(s0 + 2, r0, off, c0, doStore, px, po, sl, hbuf, vsum);
    bf_step<3, 0, true, true>(s0 + 3, r0, off, c0, doStore, px, po, sl, hbuf, vsum);
    bf_step<4, 1, true, true>(s0 + 4, r0, off, c0, doStore, px, po, sl, hbuf, vsum);
    bf_step<5, 2, true, true>(s0 + 5, r0, off, c0, doStore, px, po, sl, hbuf, vsum);
    bf_step<6, 0, true, true>(s0 + 6, r0, off, c0, doStore, px, po, sl, hbuf, vsum);
    bf_step<7, 1, true, true>(s0 + 7, r0, off, c0, doStore, px, po, sl, hbuf, vsum);
    bf_step<8, 2, true, true>(s0 + 8, r0, off, c0, doStore, px, po, sl, hbuf, vsum);
  }
  // last group: s = 63..71; final 3 steps skip prefetch
  bf_step<0, 0, true, true >(63, r0, off, c0, doStore, px, po, sl, hbuf, vsum);
  bf_step<1, 1, true, true >(64, r0, off, c0, doStore, px, po, sl, hbuf, vsum);
  bf_step<2, 2, true, true >(65, r0, off, c0, doStore, px, po, sl, hbuf, vsum);
  bf_step<3, 0, true, true >(66, r0, off, c0, doStore, px, po, sl, hbuf, vsum);
  bf_step<4, 1, true, true >(67, r0, off, c0, doStore, px, po, sl, hbuf, vsum);
  bf_step<5, 2, true, true >(68, r0, off, c0, doStore, px, po, sl, hbuf, vsum);
  bf_step<6, 0, true, false>(69, r0, off, c0, doStore, px, po, sl, hbuf, vsum);
  bf_step<7, 1, true, false>(70, r0, off, c0, doStore, px, po, sl, hbuf, vsum);
  bf_step<8, 2, true, false>(71, r0, off, c0, doStore, px, po, sl, hbuf, vsum);
}

extern "C" void kernel_launch(void* const* d_in, const int* in_sizes, int n_in,
                              void* d_out, int out_size, void* d_ws, size_t ws_size,
                              hipStream_t stream) {
  const float* x   = (const float*)d_in[0];
  float*       out = (float*)d_out;
  const int planes = out_size / (H * W);              // 8*3 = 24
  const int nMain  = planes * (H / RH) * 2;           // 24*32*2 = 1536
  const int nEdge  = planes * (H / TPB);              // 24*8 = 192
  dim3 grid(nEdge + nMain);
  dim3 block(TPB);
  hipLaunchKernelGGL(BoxFilter_kernel, grid, block, 0, stream, x, out, nEdge);
}